// Round 6
// baseline (88.305 us; speedup 1.0000x reference)
//
#include <hip/hip_runtime.h>
#include <hip/hip_bf16.h>

#define NN 8192
#define DD 64

typedef __attribute__((ext_vector_type(8))) short short8;
typedef __attribute__((ext_vector_type(4))) float floatx4;
typedef __attribute__((ext_vector_type(4))) int intx4;

// compile-time-indexed 4-way select (avoids runtime ext_vector indexing -> scratch)
__device__ __forceinline__ float sel4(floatx4 v, int r) {
    float a = (r & 1) ? v[1] : v[0];
    float b = (r & 1) ? v[3] : v[2];
    return (r & 2) ? b : a;
}

// async global->LDS, 16B per lane; LDS dest is wave-uniform base + lane*16
__device__ __forceinline__ void gload_lds16(const void* g, void* l) {
    __builtin_amdgcn_global_load_lds(
        (const __attribute__((address_space(1))) unsigned int*)g,
        (__attribute__((address_space(3))) unsigned int*)l, 16, 0, 0);
}

// LDS byte offset of a shared-memory pointer (for raw ds_read asm)
__device__ __forceinline__ unsigned lds_off(void* p) {
    return (unsigned)(unsigned long long)(__attribute__((address_space(3))) char*)p;
}

// ---------------- prep: per-row stats in fp32, Z -> bf16 ----------------
__global__ __launch_bounds__(256) void prep_kernel(const float* __restrict__ Z,
                                                   unsigned short* __restrict__ Zb,
                                                   float* __restrict__ u,
                                                   float* __restrict__ v) {
    int row = blockIdx.x * 4 + (threadIdx.x >> 6);
    int lane = threadIdx.x & 63;
    float z = Z[(size_t)row * DD + lane];
    __hip_bfloat16 zb = __float2bfloat16(z);
    Zb[(size_t)row * DD + lane] = *(unsigned short*)&zb;
    float sq = z * z;
    float s = z;
    for (int off = 32; off; off >>= 1) {
        sq += __shfl_xor(sq, off);
        s  += __shfl_xor(s,  off);
    }
    if (lane == 0) {
        const float deps2 = (float)DD * 1e-6f * 1e-6f;
        u[row] = sq + 2e-6f * s + deps2;  // i-side: sq_i + 2*eps*s_i + D*eps^2
        v[row] = sq - 2e-6f * s;          // j-side: sq_j - 2*eps*s_j
    }
}

// ---------------- main: 128x128 tile per block, 4 waves of 64x64 ----------------
// A staged per-wave into LDS in 4KB QUARTERS, double-buffered (8KB/wave, 32KB/block
// -> 4 blocks/CU). Counted vmcnt waits keep the next quarter in flight while the
// current one is consumed (T3/T4). Source columns XOR-swizzled by ((row&7)<<4);
// the swizzled ds_read_b128 is ~2-way bank-conflict (free). Swapped MFMA operands:
// lane owns (i = iBase+m*16+llo, j = jBase+n*16+lhi*4+r). Branchless softplus
// ~= e^theta; true diagonal gets exact bit-identical cancellation after the loop.
__global__ __launch_bounds__(256, 4) void main_kernel(const unsigned short* __restrict__ Zb,
                                                      const float* __restrict__ u,
                                                      const float* __restrict__ v,
                                                      const float* __restrict__ alpha,
                                                      const int* __restrict__ A,
                                                      float* __restrict__ partials) {
    __shared__ int Alds[4][2048];   // 32 KB: 8 KB (two 16x64 quarters) per wave

    int bid = blockIdx.x;
    int bi = bid >> 6;        // N / 128 = 64 tiles per dim
    int bj = bid & 63;
    int tid = threadIdx.x;
    int wid = tid >> 6;
    int lane = tid & 63;
    int wr = wid >> 1, wc = wid & 1;
    int iBase = bi * 128 + wr * 64;
    int jBase = bj * 128 + wc * 64;
    int lhi = lane >> 4;      // 0..3
    int llo = lane & 15;      // 0..15
    int kb  = lhi * 8;        // k-offset within 32-wide k-step

    // ---- issue MFMA fragment loads FIRST (L2-hot Zb), then stats, then A quarters
    short8 afrag[4][2], bfrag[4][2];
#pragma unroll
    for (int m = 0; m < 4; ++m) {
        const unsigned short* pa = &Zb[(size_t)(iBase + m * 16 + llo) * DD + kb];
        afrag[m][0] = *(const short8*)pa;
        afrag[m][1] = *(const short8*)(pa + 32);
        const unsigned short* pb = &Zb[(size_t)(jBase + m * 16 + llo) * DD + kb];
        bfrag[m][0] = *(const short8*)pb;
        bfrag[m][1] = *(const short8*)(pb + 32);
    }

    float ui[4];
#pragma unroll
    for (int m = 0; m < 4; ++m) ui[m] = u[iBase + m * 16 + llo];
    floatx4 vj[4], aj[4];
#pragma unroll
    for (int n = 0; n < 4; ++n) {
        vj[n] = *(const floatx4*)&v[jBase + n * 16 + lhi * 4];
        aj[n] = *(const floatx4*)&alpha[jBase + n * 16 + lhi * 4];
    }

    // staging geometry: quarter q covers rows q*16..q*16+15 of this wave's 64x64
    // A subtile; instr t stages rows q*16+t*4+(lane>>4); lane writes LDS at
    // buf*4096 + t*1024 + lane*16 (linear); global source column pre-swizzled.
    const int* gw = A + (size_t)iBase * NN + jBase;
    char* ldsW = (char*)&Alds[wid][0];
    int r0 = lane >> 4;
    int cs = (lane & 15) * 16;
#define LOADQ(q, buf)                                                             \
    {                                                                             \
        _Pragma("unroll") for (int t = 0; t < 4; ++t) {                           \
            int rr = (q) * 16 + t * 4 + r0;                                       \
            int colb = cs ^ ((rr & 7) << 4);                                      \
            gload_lds16((const char*)(gw + (size_t)rr * NN) + colb,               \
                        ldsW + (buf) * 4096 + t * 1024);                          \
        }                                                                         \
    }

    // pin all prior loads before the counted gload_lds sequence (vmcnt accounting)
    asm volatile("" ::: "memory");
    LOADQ(0, 0);
    LOADQ(1, 1);

    floatx4 acc[4][4];
#pragma unroll
    for (int m = 0; m < 4; ++m)
#pragma unroll
        for (int n = 0; n < 4; ++n)
            acc[m][n] = (floatx4){0.f, 0.f, 0.f, 0.f};

#pragma unroll
    for (int kk = 0; kk < 2; ++kk)
#pragma unroll
        for (int m = 0; m < 4; ++m)
#pragma unroll
            for (int n = 0; n < 4; ++n)
                acc[m][n] = __builtin_amdgcn_mfma_f32_16x16x32_bf16(
                    bfrag[n][kk], afrag[m][kk], acc[m][n], 0, 0, 0);

    // per-lane read addressing (XOR-swizzled), loop-invariant parts hoisted
    unsigned ldsBase = lds_off(&Alds[wid][0]);
    int swz = (llo & 7) << 4;
    unsigned base0 = ldsBase + (unsigned)(llo * 256);
    unsigned off4[4];
#pragma unroll
    for (int n = 0; n < 4; ++n) off4[n] = (unsigned)((n * 64 + lhi * 16) ^ swz);

    float ll = 0.f;
#pragma unroll
    for (int m = 0; m < 4; ++m) {
        // quarter m arrived; quarter m+1 (and later m+2) stay in flight
        if (m < 3) asm volatile("s_waitcnt vmcnt(4)" ::: "memory");
        else       asm volatile("s_waitcnt vmcnt(0)" ::: "memory");

        unsigned bm = base0 + (unsigned)((m & 1) * 4096);
        intx4 Av[4];
#pragma unroll
        for (int n = 0; n < 4; ++n)
            asm volatile("ds_read_b128 %0, %1" : "=&v"(Av[n]) : "v"(bm + off4[n]));
        asm volatile("s_waitcnt lgkmcnt(0)" ::: "memory");
        // just-freed buffer can now take the next quarter
        if (m == 0) LOADQ(2, 0);
        if (m == 1) LOADQ(3, 1);
        __builtin_amdgcn_sched_barrier(0);

#pragma unroll
        for (int n = 0; n < 4; ++n) {
#pragma unroll
            for (int r = 0; r < 4; ++r) {
                float g = acc[m][n][r];
                float d2 = fmaf(-2.f, g, ui[m] + vj[n][r]);
                float zd = __builtin_amdgcn_sqrtf(fmaxf(d2, 0.f));
                float th = aj[n][r] - zd;
                float sp = __expf(th);                 // softplus approx, theta << -4
                ll += (Av[n][r] ? th : 0.f) - sp;      // A is {0,1}: select, no cvt
            }
        }
    }

    // exact diagonal cancellation: add back the e^theta the loop subtracted for i==j.
    if (__builtin_expect(bi == bj, 0)) {
        if (wr == wc && (llo >> 2) == lhi) {
            int r = llo & 3;
#pragma unroll
            for (int m = 0; m < 4; ++m) {
                float g = sel4(acc[m][m], r);
                float d2 = fmaf(-2.f, g, ui[m] + sel4(vj[m], r));
                float zd = __builtin_amdgcn_sqrtf(fmaxf(d2, 0.f));
                float th = sel4(aj[m], r) - zd;
                ll += __expf(th);                      // bit-identical -> exact cancel
            }
        }
    }

    // wave reduce, then block reduce through (now-consumed) LDS
    for (int off = 32; off; off >>= 1) ll += __shfl_xor(ll, off);
    if (lane == 0) *(float*)&Alds[wid][0] = ll;
    __syncthreads();
    if (tid == 0)
        partials[bid] = *(float*)&Alds[0][0] + *(float*)&Alds[1][0]
                      + *(float*)&Alds[2][0] + *(float*)&Alds[3][0];
}

// ---------------- final deterministic reduction ----------------
__global__ __launch_bounds__(256) void final_kernel(const float* __restrict__ partials,
                                                    float* __restrict__ out) {
    int tid = threadIdx.x;
    float sum = 0.f;
    for (int idx = tid; idx < 4096; idx += 256) sum += partials[idx];
    for (int off = 32; off; off >>= 1) sum += __shfl_xor(sum, off);
    __shared__ float red[4];
    if ((tid & 63) == 0) red[tid >> 6] = sum;
    __syncthreads();
    if (tid == 0) out[0] = 0.5f * (red[0] + red[1] + red[2] + red[3]);
}

extern "C" void kernel_launch(void* const* d_in, const int* in_sizes, int n_in,
                              void* d_out, int out_size, void* d_ws, size_t ws_size,
                              hipStream_t stream) {
    const int*   A     = (const int*)d_in[0];
    const float* alpha = (const float*)d_in[1];
    const float* Z     = (const float*)d_in[2];
    float* out = (float*)d_out;

    char* ws = (char*)d_ws;
    unsigned short* Zb = (unsigned short*)ws;                    // N*D*2 = 1 MB
    float* u        = (float*)(ws + (size_t)NN * DD * 2);        // 32 KB
    float* v        = u + NN;                                    // 32 KB
    float* partials = v + NN;                                    // 4096 floats

    prep_kernel<<<NN / 4, 256, 0, stream>>>(Z, Zb, u, v);
    main_kernel<<<4096, 256, 0, stream>>>(Zb, u, v, alpha, A, partials);
    final_kernel<<<1, 256, 0, stream>>>(partials, out);
}

// Round 7
// 71.256 us; speedup vs baseline: 1.2393x; 1.2393x over previous
//
#include <hip/hip_runtime.h>
#include <hip/hip_bf16.h>

#define NN 8192
#define DD 64
#define NT 16            // j-tiles per block

typedef __attribute__((ext_vector_type(8))) short short8;
typedef __attribute__((ext_vector_type(4))) float floatx4;
typedef __attribute__((ext_vector_type(4))) int intx4;

// compile-time-indexed 4-way select (avoids runtime ext_vector indexing -> scratch)
__device__ __forceinline__ float sel4(floatx4 v, int r) {
    float a = (r & 1) ? v[1] : v[0];
    float b = (r & 1) ? v[3] : v[2];
    return (r & 2) ? b : a;
}

// async global->LDS, 16B per lane; LDS dest is wave-uniform base + lane*16
__device__ __forceinline__ void gload_lds16(const void* g, void* l) {
    __builtin_amdgcn_global_load_lds(
        (const __attribute__((address_space(1))) unsigned int*)g,
        (__attribute__((address_space(3))) unsigned int*)l, 16, 0, 0);
}

// ---------------- prep: per-row stats in fp32, Z -> bf16 ----------------
__global__ __launch_bounds__(256) void prep_kernel(const float* __restrict__ Z,
                                                   unsigned short* __restrict__ Zb,
                                                   float* __restrict__ u,
                                                   float* __restrict__ v) {
    int row = blockIdx.x * 4 + (threadIdx.x >> 6);
    int lane = threadIdx.x & 63;
    float z = Z[(size_t)row * DD + lane];
    __hip_bfloat16 zb = __float2bfloat16(z);
    Zb[(size_t)row * DD + lane] = *(unsigned short*)&zb;
    float sq = z * z;
    float s = z;
    for (int off = 32; off; off >>= 1) {
        sq += __shfl_xor(sq, off);
        s  += __shfl_xor(s,  off);
    }
    if (lane == 0) {
        const float deps2 = (float)DD * 1e-6f * 1e-6f;
        u[row] = sq + 2e-6f * s + deps2;  // i-side: sq_i + 2*eps*s_i + D*eps^2
        v[row] = sq - 2e-6f * s;          // j-side: sq_j - 2*eps*s_j
    }
}

// ---------------- main: PERSISTENT blocks, 512 total (2/CU) ----------------
// Block owns i-rows [bi*128, +128) and loops NT=16 j-tiles of width 64.
// Wave w owns i-rows [bi*128 + w*32, +32). Per tile, the wave's 32x64 A-subtile
// (8 KB) is staged via global_load_lds into one of two private LDS buffers;
// stage(t+1) is issued, then ONE counted vmcnt(8) guarantees stage(t) arrived
// while stage(t+1) stays in flight across the whole tile's compute. No barriers
// in the loop (waves own disjoint LDS). XOR swizzle ((row&7)<<4) on the staged
// source column kills the 16-way ds_read bank conflict. Swapped MFMA operands:
// lane owns (i = iBaseW+m*16+llo, j = jBase+n*16+lhi*4+r). Branchless softplus
// ~= e^theta; true diagonal gets exact bit-identical in-loop cancellation.
__global__ __launch_bounds__(256, 2) void main_kernel(const unsigned short* __restrict__ Zb,
                                                      const float* __restrict__ u,
                                                      const float* __restrict__ v,
                                                      const float* __restrict__ alpha,
                                                      const int* __restrict__ A,
                                                      float* __restrict__ partials) {
    __shared__ char Alds[4][2][8192];   // 64 KB: per wave, two 8 KB tile buffers
    __shared__ float red[4];

    int blk = blockIdx.x;
    int bi = blk >> 3;                  // 0..63 -> i-rows bi*128..+128
    int jg = blk & 7;                   // 0..7  -> j-cols jg*1024..+1024
    int tid = threadIdx.x;
    int wid = tid >> 6;
    int lane = tid & 63;
    int iBaseW = bi * 128 + wid * 32;
    int jBase0 = jg * (NT * 64);
    int lhi = lane >> 4;                // 0..3
    int llo = lane & 15;                // 0..15
    int kb  = lhi * 8;                  // k-offset within 32-wide k-step

    // ---- i-side fragments + stats, loaded once (L2-hot)
    short8 af[2][2];
#pragma unroll
    for (int m = 0; m < 2; ++m) {
        const unsigned short* pa = &Zb[(size_t)(iBaseW + m * 16 + llo) * DD + kb];
        af[m][0] = *(const short8*)pa;
        af[m][1] = *(const short8*)(pa + 32);
    }
    float ui[2];
#pragma unroll
    for (int m = 0; m < 2; ++m) ui[m] = u[iBaseW + m * 16 + llo];

    // ---- staging geometry: instr t2 stages rows t2*4+(lane>>4) of the 32x64
    // subtile; lane writes LDS at buf*8192 + t2*1024 + lane*16 (linear);
    // global source column pre-swizzled so swizzled reads are conflict-free.
    char* ldsW = (char*)&Alds[wid][0][0];
    const int r0 = lane >> 4;
    const int cs = (lane & 15) * 16;
#define STAGE(t, buf)                                                             \
    {                                                                             \
        const int* gw = A + (size_t)iBaseW * NN + jBase0 + (t) * 64;              \
        _Pragma("unroll") for (int t2 = 0; t2 < 8; ++t2) {                        \
            int rr = t2 * 4 + r0;                                                 \
            int colb = cs ^ ((rr & 7) << 4);                                      \
            gload_lds16((const char*)(gw + (size_t)rr * NN) + colb,               \
                        ldsW + (buf) * 8192 + t2 * 1024);                         \
        }                                                                         \
    }

    asm volatile("" ::: "memory");
    STAGE(0, 0);

    int swz = (llo & 7) << 4;
    unsigned off4[4];
#pragma unroll
    for (int n = 0; n < 4; ++n) off4[n] = (unsigned)((n * 64 + lhi * 16) ^ swz);

    float ll = 0.f;
    for (int t = 0; t < NT; ++t) {
        // issue next tile's stage, then one counted wait: the 8 newest vmem ops
        // are stage(t+1), so <=8 outstanding => stage(t) fully arrived.
        if (t + 1 < NT) {
            STAGE(t + 1, (t + 1) & 1);
            asm volatile("s_waitcnt vmcnt(8)" ::: "memory");
        } else {
            asm volatile("s_waitcnt vmcnt(0)" ::: "memory");
        }

        int jBase = jBase0 + t * 64;

        // j-side fragments + stats for this tile (L2-hot)
        short8 bf[4][2];
#pragma unroll
        for (int n = 0; n < 4; ++n) {
            const unsigned short* pb = &Zb[(size_t)(jBase + n * 16 + llo) * DD + kb];
            bf[n][0] = *(const short8*)pb;
            bf[n][1] = *(const short8*)(pb + 32);
        }
        floatx4 vj[4], aj[4];
#pragma unroll
        for (int n = 0; n < 4; ++n) {
            vj[n] = *(const floatx4*)&v[jBase + n * 16 + lhi * 4];
            aj[n] = *(const floatx4*)&alpha[jBase + n * 16 + lhi * 4];
        }

        floatx4 acc[2][4];
#pragma unroll
        for (int m = 0; m < 2; ++m)
#pragma unroll
            for (int n = 0; n < 4; ++n)
                acc[m][n] = (floatx4){0.f, 0.f, 0.f, 0.f};
#pragma unroll
        for (int kk = 0; kk < 2; ++kk)
#pragma unroll
            for (int m = 0; m < 2; ++m)
#pragma unroll
                for (int n = 0; n < 4; ++n)
                    acc[m][n] = __builtin_amdgcn_mfma_f32_16x16x32_bf16(
                        bf[n][kk], af[m][kk], acc[m][n], 0, 0, 0);

        // consume staged A from buf t&1 (plain C++ ds_read_b128, compiler-scheduled)
        const char* bufB = ldsW + (t & 1) * 8192 + llo * 256;
#pragma unroll
        for (int m = 0; m < 2; ++m) {
            intx4 Av[4];
#pragma unroll
            for (int n = 0; n < 4; ++n)
                Av[n] = *(const intx4*)(bufB + m * 4096 + off4[n]);
#pragma unroll
            for (int n = 0; n < 4; ++n) {
#pragma unroll
                for (int r = 0; r < 4; ++r) {
                    float g = acc[m][n][r];
                    float d2 = fmaf(-2.f, g, ui[m] + vj[n][r]);
                    float zd = __builtin_amdgcn_sqrtf(fmaxf(d2, 0.f));
                    float th = aj[n][r] - zd;
                    float sp = __expf(th);             // softplus approx, theta << -4
                    ll += (Av[n][r] ? th : 0.f) - sp;
                }
            }
        }

        // exact diagonal cancellation (wave-uniform rare guard): add back the
        // e^theta subtracted for i==j, recomputed bit-identically.
        int dd = iBaseW - jBase;                       // n*16 - m*16 == dd on diag frags
        if (__builtin_expect(dd >= -16 && dd <= 48, 0)) {
            if ((llo >> 2) == lhi) {
                int r = llo & 3;
#pragma unroll
                for (int m = 0; m < 2; ++m)
#pragma unroll
                    for (int n = 0; n < 4; ++n)
                        if (n * 16 - m * 16 == dd) {   // uniform per fragment
                            float g = sel4(acc[m][n], r);
                            float d2 = fmaf(-2.f, g, ui[m] + sel4(vj[n], r));
                            float zd = __builtin_amdgcn_sqrtf(fmaxf(d2, 0.f));
                            float th = sel4(aj[n], r) - zd;
                            ll += __expf(th);          // bit-identical -> exact cancel
                        }
            }
        }
    }

    // wave reduce then block reduce (fixed order -> deterministic)
    for (int off = 32; off; off >>= 1) ll += __shfl_xor(ll, off);
    if (lane == 0) red[wid] = ll;
    __syncthreads();
    if (tid == 0) partials[blk] = red[0] + red[1] + red[2] + red[3];
}

// ---------------- final deterministic reduction ----------------
__global__ __launch_bounds__(256) void final_kernel(const float* __restrict__ partials,
                                                    float* __restrict__ out) {
    int tid = threadIdx.x;
    float sum = 0.f;
    for (int idx = tid; idx < 512; idx += 256) sum += partials[idx];
    for (int off = 32; off; off >>= 1) sum += __shfl_xor(sum, off);
    __shared__ float red[4];
    if ((tid & 63) == 0) red[tid >> 6] = sum;
    __syncthreads();
    if (tid == 0) out[0] = 0.5f * (red[0] + red[1] + red[2] + red[3]);
}

extern "C" void kernel_launch(void* const* d_in, const int* in_sizes, int n_in,
                              void* d_out, int out_size, void* d_ws, size_t ws_size,
                              hipStream_t stream) {
    const int*   A     = (const int*)d_in[0];
    const float* alpha = (const float*)d_in[1];
    const float* Z     = (const float*)d_in[2];
    float* out = (float*)d_out;

    char* ws = (char*)d_ws;
    unsigned short* Zb = (unsigned short*)ws;                    // N*D*2 = 1 MB
    float* u        = (float*)(ws + (size_t)NN * DD * 2);        // 32 KB
    float* v        = u + NN;                                    // 32 KB
    float* partials = v + NN;                                    // 512 floats

    prep_kernel<<<NN / 4, 256, 0, stream>>>(Z, Zb, u, v);
    main_kernel<<<512, 256, 0, stream>>>(Zb, u, v, alpha, A, partials);
    final_kernel<<<1, 256, 0, stream>>>(partials, out);
}